// Round 9
// baseline (175.176 us; speedup 1.0000x reference)
//
#include <hip/hip_runtime.h>

typedef __bf16 bf16x8 __attribute__((ext_vector_type(8)));
typedef __bf16 bf16x4 __attribute__((ext_vector_type(4)));
typedef float f32x4 __attribute__((ext_vector_type(4)));
typedef short s16x4 __attribute__((ext_vector_type(4)));

#define QSCALE 0.18033688011112042f /* 0.125 * log2(e) */

__device__ __forceinline__ void gload16(const void* g, void* l) {
  __builtin_amdgcn_global_load_lds((const __attribute__((address_space(1))) void*)g,
                                   (__attribute__((address_space(3))) void*)l, 16, 0, 0);
}

__device__ __forceinline__ float fexp2(float x) {
#if __has_builtin(__builtin_amdgcn_exp2f)
  return __builtin_amdgcn_exp2f(x);
#else
  return exp2f(x);
#endif
}

__device__ __forceinline__ f32x4 mfma16(bf16x8 a, bf16x8 b, f32x4 c) {
  return __builtin_amdgcn_mfma_f32_16x16x32_bf16(a, b, c, 0, 0, 0);
}

// 16x16x16 bf16 MFMA (k=16): A row=lane&15,k=(lane>>4)*4+j; B col=lane&15,
// same k map; C standard. Guarded fallbacks keep any toolchain compiling;
// all paths are A/B-slot-consistent so results are identical.
__device__ __forceinline__ f32x4 mfma16k16(bf16x4 a, bf16x4 b, f32x4 c) {
#if __has_builtin(__builtin_amdgcn_mfma_f32_16x16x16_bf16)
  return __builtin_amdgcn_mfma_f32_16x16x16_bf16(a, b, c, 0, 0, 0);
#elif __has_builtin(__builtin_amdgcn_mfma_f32_16x16x16bf16_1k)
  union { bf16x4 h; s16x4 s; } ua, ub;
  ua.h = a; ub.h = b;
  return __builtin_amdgcn_mfma_f32_16x16x16bf16_1k(ua.s, ub.s, c, 0, 0, 0);
#else
  // zero-pad into 16x16x32: B high half = 0 so A high half is don't-care
  union { bf16x4 q[2]; bf16x8 v; } a8, b8;
  a8.q[0] = a; a8.q[1] = a;
  bf16x4 z;
  z[0] = (__bf16)0.f; z[1] = (__bf16)0.f; z[2] = (__bf16)0.f; z[3] = (__bf16)0.f;
  b8.q[0] = b; b8.q[1] = z;
  return __builtin_amdgcn_mfma_f32_16x16x32_bf16(a8.v, b8.v, c, 0, 0, 0);
#endif
}

// pack two f32 -> bf16x2 word
__device__ __forceinline__ unsigned pkbf(float a, float b) {
  union { __bf16 h[2]; unsigned u; } t;
  t.h[0] = (__bf16)a; t.h[1] = (__bf16)b;
  return t.u;
}

// ---------------------------------------------------------------- converts
__global__ __launch_bounds__(256) void k_cvt_x(const float4* __restrict__ x,
                                               bf16x4* __restrict__ xb) {
  int i = blockIdx.x * 256 + threadIdx.x;  // grid sized exactly
  float4 v = x[i];
  bf16x4 o;
  o[0] = (__bf16)v.x; o[1] = (__bf16)v.y; o[2] = (__bf16)v.z; o[3] = (__bf16)v.w;
  xb[i] = o;
}

// Build W_qkv^T [2304][768] bf16 (row n = (t,h,e), contiguous over d) + bias[2304]
__global__ __launch_bounds__(256) void k_cvt_wqkv(
    const float* __restrict__ Wq, const float* __restrict__ Wk,
    const float* __restrict__ Wv, const float* __restrict__ bq,
    const float* __restrict__ bk, const float* __restrict__ bv,
    __bf16* __restrict__ Wt, float* __restrict__ bias) {
  int g = blockIdx.x * 256 + threadIdx.x;  // 2304*192
  int n = g / 192;
  int d4 = g - n * 192;
  int d = d4 * 4;
  int t = n / 768;
  int rr = n - t * 768;
  int h = rr >> 6, e = rr & 63;
  const float* W = (t == 0) ? Wq : ((t == 1) ? Wk : Wv);
  const float* bs = (t == 0) ? bq : ((t == 1) ? bk : bv);
  bf16x4 o;
#pragma unroll
  for (int i = 0; i < 4; ++i) o[i] = (__bf16)W[(size_t)(h * 768 + d + i) * 64 + e];
  *(bf16x4*)(Wt + (size_t)n * 768 + d) = o;
  if (d4 == 0) bias[n] = bs[h * 64 + e];
}

// Wo^T [768][768] bf16
__global__ __launch_bounds__(256) void k_cvt_wo(const float* __restrict__ Wo,
                                                __bf16* __restrict__ Wt) {
  int g = blockIdx.x * 256 + threadIdx.x;  // 768*192
  int n = g / 192;
  int d4 = g - n * 192;
  int d = d4 * 4;
  bf16x4 o;
#pragma unroll
  for (int i = 0; i < 4; ++i) o[i] = (__bf16)Wo[(size_t)(d + i) * 768 + n];
  *(bf16x4*)(Wt + (size_t)n * 768 + d) = o;
}

// ---------------------------------------------------------------- GEMM
// [R5-proven form, unchanged]
template <int MODE>
__global__ __launch_bounds__(256, 2) void k_gemm(
    const __bf16* __restrict__ A, const __bf16* __restrict__ Bt,
    const float* __restrict__ bias, __bf16* __restrict__ Qd,
    __bf16* __restrict__ Kd, __bf16* __restrict__ VTd,
    float* __restrict__ outF) {
  constexpr int KD = 768;
  __shared__ __bf16 As[2][128 * 64];
  __shared__ __bf16 Bs[2][128 * 64];
  const int tid = threadIdx.x, lane = tid & 63, wid = tid >> 6;
  const int wr = wid >> 1, wc = wid & 1;
  const int bm = blockIdx.x, bn = blockIdx.y;
  const f32x4 z4 = {0.f, 0.f, 0.f, 0.f};
  f32x4 acc[4][4];
#pragma unroll
  for (int a = 0; a < 4; ++a)
#pragma unroll
    for (int b = 0; b < 4; ++b) acc[a][b] = z4;

  const char* Ab = (const char*)A + (size_t)bm * 128 * (KD * 2);
  const char* Bb = (const char*)Bt + (size_t)bn * 128 * (KD * 2);

  auto stage = [&](int kb, int buf) {
#pragma unroll
    for (int i = 0; i < 4; ++i) {
      int o = (wid * 4 + i) * 1024 + lane * 16;
      int row = o >> 7;
      int col = (o & 127) ^ ((row & 7) << 4);  // pre-swizzled source (G21)
      gload16(Ab + (size_t)row * (KD * 2) + kb * 128 + col,
              (char*)As[buf] + (wid * 4 + i) * 1024);
      gload16(Bb + (size_t)row * (KD * 2) + kb * 128 + col,
              (char*)Bs[buf] + (wid * 4 + i) * 1024);
    }
  };

  stage(0, 0);  // prologue

  for (int kb = 0; kb < KD / 64; ++kb) {
    const int cur = kb & 1;
    if (kb < KD / 64 - 1) {
      stage(kb + 1, cur ^ 1);  // next tile in flight during compute
      asm volatile("s_waitcnt vmcnt(8)" ::: "memory");  // this tile's 8 done
    } else {
      asm volatile("s_waitcnt vmcnt(0)" ::: "memory");
    }
    __builtin_amdgcn_s_barrier();
#pragma unroll
    for (int ks = 0; ks < 2; ++ks) {
      bf16x8 af[4], bfr[4];
#pragma unroll
      for (int ar = 0; ar < 4; ++ar) {
        int rl = wr * 64 + ar * 16 + (lane & 15);
        int byt = rl * 128 + ((ks * 64 + (lane >> 4) * 16) ^ ((rl & 7) << 4));
        af[ar] = *(const bf16x8*)((const char*)As[cur] + byt);
      }
#pragma unroll
      for (int bc = 0; bc < 4; ++bc) {
        int rl = wc * 64 + bc * 16 + (lane & 15);
        int byt = rl * 128 + ((ks * 64 + (lane >> 4) * 16) ^ ((rl & 7) << 4));
        bfr[bc] = *(const bf16x8*)((const char*)Bs[cur] + byt);
      }
#pragma unroll
      for (int ar = 0; ar < 4; ++ar)
#pragma unroll
        for (int bc = 0; bc < 4; ++bc)
          acc[ar][bc] = mfma16(af[ar], bfr[bc], acc[ar][bc]);
    }
    __builtin_amdgcn_s_barrier();
  }

#pragma unroll
  for (int ar = 0; ar < 4; ++ar) {
#pragma unroll
    for (int bc = 0; bc < 4; ++bc) {
      int n = bn * 128 + wc * 64 + bc * 16 + (lane & 15);
      float bval = bias[n];
#pragma unroll
      for (int r = 0; r < 4; ++r) {
        int m = bm * 128 + wr * 64 + ar * 16 + (lane >> 4) * 4 + r;
        float val = acc[ar][bc][r] + bval;
        if constexpr (MODE == 0) {
          int t = n / 768;
          int rr = n - t * 768;
          int h = rr >> 6, e = rr & 63;
          int b = m >> 11, s = m & 2047;
          size_t bh = (size_t)(b * 12 + h);
          if (t == 0)
            Qd[(bh * 2048 + s) * 64 + e] = (__bf16)(val * QSCALE);
          else if (t == 1)
            Kd[(bh * 2048 + s) * 64 + e] = (__bf16)val;
          else
            VTd[(bh * 64 + e) * 2048 + s] = (__bf16)val;
        } else {
          outF[(size_t)m * 768 + n] = val;
        }
      }
    }
  }
}

// ---------------------------------------------------------------- flash attn
// R9 "KSPLIT": waves split the KV (k) dimension, not q.
// Diagnosis: R5-R8 all plateau at ~73us because all 4 waves redundantly read
// the ENTIRE K/V tile from LDS (192 b128/CU-iter x ~12cy > iter wall) -> LDS
// read-BW-bound. Fix: wave w owns kv-rows w*16..w*16+15 for ALL 64 q-rows:
//   - K-frag reads/wave-iter: 2 b128 (was 8); V: 4 b64 (was 8 b128)
//   - QK: mfma(K,Q) with ct==wid; P[k=w16+g*4+r][q] is EXACTLY the 16x16x16
//     B-operand layout (k=g*4+j) -> NO permlane redistribution at all
//   - PV: 16x16x16 MFMA (k=16), V^T b64 A-frags
//   - epilogue: one-time 4-wave O/l reduction via LDS (reuses Ks as scratch)
// QBLK=64, grid 32x48=1536 (2 clean rounds of 3 blocks/CU), XCD swizzle,
// NO-MAX softmax (log2-domain scores), triple-buffered K/V staging with
// counted vmcnt(4), depth-2 pipeline {V(t),SM(t) | barrier | QK(t+1) | PV(t)}.
__global__ __launch_bounds__(256, 3) void k_attn(const __bf16* __restrict__ Qg,
                                                 const __bf16* __restrict__ Kg,
                                                 const __bf16* __restrict__ Vg,
                                                 __bf16* __restrict__ AO) {
  constexpr int S = 2048;
  constexpr int NT = S / 64;  // 32 kv tiles
  __shared__ __bf16 Ks[3][64 * 64];
  __shared__ __bf16 Vs[3][64 * 64];
  const int tid = threadIdx.x, lane = tid & 63, wid = tid >> 6;
  const int q = lane & 15, g = lane >> 4;
  const int q7s = (q & 7) << 4;
  // T1 bijective XCD swizzle: 1536 blocks = 8 XCD x 192; 6 bh per XCD -> 3MB<L2
  const int lin = blockIdx.x + blockIdx.y * 32;  // 0..1535
  const int xcd = lin & 7, pos = lin >> 3;       // pos 0..191
  const int bh = xcd * 6 + (pos >> 5);
  const int qt = pos & 31;
  const int bb = bh / 12, hh = bh - bb * 12;
  const size_t hoff = (size_t)bh * S * 64;
  const int q0 = qt * 64;  // block owns 64 q-rows; ALL waves cover all of them

  // Q as B-fragments (16x16x32): col=q, k-dim d = ks*32 + g*8..+7; rt = q-tile
  bf16x8 qb[4][2];
#pragma unroll
  for (int rt = 0; rt < 4; ++rt)
#pragma unroll
    for (int ks = 0; ks < 2; ++ks)
      qb[rt][ks] = *(const bf16x8*)(Qg + hoff + (size_t)(q0 + rt * 16 + q) * 64 +
                                    ks * 32 + g * 8);

  const f32x4 z4 = {0.f, 0.f, 0.f, 0.f};
  f32x4 acc[4][4];  // [rt][et]: O[e=et*16+g*4+r][q-row rt*16+q] (k-partial)
#pragma unroll
  for (int a = 0; a < 4; ++a)
#pragma unroll
    for (int b = 0; b < 4; ++b) acc[a][b] = z4;
  float l_p[4] = {0.f, 0.f, 0.f, 0.f};  // k-partial row sums

  const char* Kb = (const char*)(Kg + hoff);
  const char* Vb = (const char*)(Vg + (size_t)bh * 64 * S);

  // ---- staging: 4 gload16/thread per tile (2 K + 2 V) — same as R8
  auto stage = [&](int kv, int buf) {
#pragma unroll
    for (int i = 0; i < 2; ++i) {
      int o = (wid * 2 + i) * 1024 + lane * 16;
      int row = o >> 7;
      int col = (o & 127) ^ ((row & 7) << 4);  // pre-swizzled source (G21)
      gload16(Kb + (size_t)(kv * 64 + row) * 128 + col,
              (char*)Ks[buf] + (wid * 2 + i) * 1024);
      gload16(Vb + (size_t)row * (S * 2) + (size_t)kv * 128 + col,
              (char*)Vs[buf] + (wid * 2 + i) * 1024);
    }
  };

  // QK^T for one tile, wave's k-quarter only: sa[rt], row k_local = g*4+r,
  // col = q.  K A-frag rows rl = wid*16 + q (2 b128 reads total).
  auto qk = [&](const char* Kc, f32x4 (&sa)[4]) {
#pragma unroll
    for (int rt = 0; rt < 4; ++rt) sa[rt] = z4;
    const int rl = wid * 16 + q;
    __builtin_amdgcn_s_setprio(1);
#pragma unroll
    for (int ks = 0; ks < 2; ++ks) {
      bf16x8 ka = *(const bf16x8*)(Kc + rl * 128 + ((ks * 64 + g * 16) ^ q7s));
#pragma unroll
      for (int rt = 0; rt < 4; ++rt) sa[rt] = mfma16(ka, qb[rt][ks], sa[rt]);
    }
    __builtin_amdgcn_s_setprio(0);
  };

  // prologue: tiles 0,1 in flight; wait tile 0
  stage(0, 0);
  stage(1, 1);
  asm volatile("s_waitcnt vmcnt(4)" ::: "memory");
  __builtin_amdgcn_s_barrier();

  f32x4 sa[4];
  qk((const char*)Ks[0], sa);  // QK(0)

  int bc = 0;  // buffer holding tile kv
  for (int kv = 0; kv < NT; ++kv) {
    const int b1 = (bc == 2) ? 0 : bc + 1;
    const int b2 = (b1 == 2) ? 0 : b1 + 1;
    if (kv < NT - 2) stage(kv + 2, b2);
    const char* Vc = (const char*)Vs[bc];

    // ---- V(t) k-quarter to registers: A-frags of 16x16x16, row e, k=w16+g4+j
    bf16x4 vf[4];
#pragma unroll
    for (int et = 0; et < 4; ++et) {
      int rl = et * 16 + q;
      vf[et] = *(const bf16x4*)(Vc + rl * 128 + ((wid * 32 + g * 8) ^ q7s));
    }

    // ---- SM(t): p = exp2(s); cvt_pk -> PV B-frags DIRECTLY (no permlane)
    bf16x4 pb[4];
#pragma unroll
    for (int rt = 0; rt < 4; ++rt) {
      float p0 = fexp2(sa[rt][0]);
      float p1 = fexp2(sa[rt][1]);
      float p2 = fexp2(sa[rt][2]);
      float p3 = fexp2(sa[rt][3]);
      l_p[rt] += (p0 + p1) + (p2 + p3);
      union { unsigned u[2]; bf16x4 v; } f;
      f.u[0] = pkbf(p0, p1);
      f.u[1] = pkbf(p2, p3);
      pb[rt] = f.v;
    }

    // ---- tile t+1 ready; QK(t+1) interleaves with PV(t)
    if (kv < NT - 1) {
      if (kv < NT - 2) {
        asm volatile("s_waitcnt vmcnt(4)" ::: "memory");  // own stage(t+1) done
      } else {
        asm volatile("s_waitcnt vmcnt(0)" ::: "memory");  // last tile
      }
      __builtin_amdgcn_s_barrier();  // all waves: t+1 ready, tile t-1 free
      qk((const char*)Ks[b1], sa);
    }

    // ---- PV(t): O[e][q] += V^T[e][k] P[k][q] over wave's 16 k (register-only)
    __builtin_amdgcn_s_setprio(1);
#pragma unroll
    for (int rt = 0; rt < 4; ++rt)
#pragma unroll
      for (int et = 0; et < 4; ++et)
        acc[rt][et] = mfma16k16(vf[et], pb[rt], acc[rt][et]);
    __builtin_amdgcn_s_setprio(0);
    bc = b1;
  }

  // ---- epilogue: cross-wave O/l reduction via LDS, then wave 3 stores.
  __builtin_amdgcn_s_barrier();  // all LDS K/V reads done; reuse Ks as scratch
  float* R = (float*)&Ks[0][0];  // [64 q][stride 68] f32  (17.4 KB < 24 KB)
  float* Rl = R + 64 * 68;       // [64] f32 row sums
  float lr[4];
#pragma unroll
  for (int rt = 0; rt < 4; ++rt) {  // reduce l over g-groups in-wave
    float s = l_p[rt];
    s += __shfl_xor(s, 16, 64);
    s += __shfl_xor(s, 32, 64);
    lr[rt] = s;
  }
  for (int w2 = 0; w2 < 4; ++w2) {
    if (wid == w2) {
      if (w2 == 0) {
#pragma unroll
        for (int rt = 0; rt < 4; ++rt) {
#pragma unroll
          for (int et = 0; et < 4; ++et)
            *(f32x4*)&R[(rt * 16 + q) * 68 + et * 16 + g * 4] = acc[rt][et];
          if (g == 0) Rl[rt * 16 + q] = lr[rt];
        }
      } else {
#pragma unroll
        for (int rt = 0; rt < 4; ++rt) {
#pragma unroll
          for (int et = 0; et < 4; ++et) {
            int idx = (rt * 16 + q) * 68 + et * 16 + g * 4;
            f32x4 t = *(f32x4*)&R[idx];
            t += acc[rt][et];
            if (w2 < 3)
              *(f32x4*)&R[idx] = t;
            else
              acc[rt][et] = t;
          }
          if (w2 < 3) {
            if (g == 0) Rl[rt * 16 + q] += lr[rt];
          } else {
            lr[rt] = Rl[rt * 16 + q] + lr[rt];  // all lanes read (broadcast)
          }
        }
      }
    }
    __builtin_amdgcn_s_barrier();
  }
  if (wid == 3) {
#pragma unroll
    for (int rt = 0; rt < 4; ++rt) {
      float inv = 1.0f / lr[rt];
      int srow = q0 + rt * 16 + q;
#pragma unroll
      for (int et = 0; et < 4; ++et) {
        bf16x4 ov;
#pragma unroll
        for (int r = 0; r < 4; ++r) ov[r] = (__bf16)(acc[rt][et][r] * inv);
        *(bf16x4*)(AO + ((size_t)bb * S + srow) * 768 + hh * 64 + et * 16 +
                   g * 4) = ov;
      }
    }
  }
}

// ---------------------------------------------------------------- launch
extern "C" void kernel_launch(void* const* d_in, const int* in_sizes, int n_in,
                              void* d_out, int out_size, void* d_ws,
                              size_t ws_size, hipStream_t stream) {
  const float* x = (const float*)d_in[0];
  const float* Wq = (const float*)d_in[1];
  const float* bq = (const float*)d_in[2];
  const float* Wk = (const float*)d_in[3];
  const float* bk = (const float*)d_in[4];
  const float* Wv = (const float*)d_in[5];
  const float* bv = (const float*)d_in[6];
  const float* Wo = (const float*)d_in[7];
  const float* bo = (const float*)d_in[8];
  float* out = (float*)d_out;
  char* ws = (char*)d_ws;

  // workspace layout (55.06 MB total)
  __bf16* xb = (__bf16*)(ws + 0);            // 12,582,912  (also attn_out later)
  __bf16* wqkv = (__bf16*)(ws + 12582912);   //  3,538,944
  __bf16* wot = (__bf16*)(ws + 16121856);    //  1,179,648
  float* biasq = (float*)(ws + 17301504);    //      9,216
  __bf16* Qb = (__bf16*)(ws + 17310720);     // 12,582,912
  __bf16* Kb = (__bf16*)(ws + 29893632);     // 12,582,912
  __bf16* VT = (__bf16*)(ws + 42476544);     // 12,582,912 -> end 55,059,456

  k_cvt_x<<<6144, 256, 0, stream>>>((const float4*)x, (bf16x4*)xb);
  k_cvt_wqkv<<<1728, 256, 0, stream>>>(Wq, Wk, Wv, bq, bk, bv, wqkv, biasq);
  k_cvt_wo<<<576, 256, 0, stream>>>(Wo, wot);
  k_gemm<0><<<dim3(64, 18), 256, 0, stream>>>(xb, wqkv, biasq, Qb, Kb, VT,
                                              nullptr);
  k_attn<<<dim3(32, 48), 256, 0, stream>>>(Qb, Kb, VT, xb /*attn_out*/);
  k_gemm<1><<<dim3(64, 6), 256, 0, stream>>>(xb, wot, bo, nullptr, nullptr,
                                             nullptr, out);
}

// Round 10
// 148.172 us; speedup vs baseline: 1.1823x; 1.1823x over previous
//
#include <hip/hip_runtime.h>

typedef __bf16 bf16x8 __attribute__((ext_vector_type(8)));
typedef __bf16 bf16x4 __attribute__((ext_vector_type(4)));
typedef float f32x4 __attribute__((ext_vector_type(4)));

#define QSCALE 0.18033688011112042f /* 0.125 * log2(e) */

__device__ __forceinline__ void gload16(const void* g, void* l) {
  __builtin_amdgcn_global_load_lds((const __attribute__((address_space(1))) void*)g,
                                   (__attribute__((address_space(3))) void*)l, 16, 0, 0);
}

__device__ __forceinline__ float fexp2(float x) {
#if __has_builtin(__builtin_amdgcn_exp2f)
  return __builtin_amdgcn_exp2f(x);
#else
  return exp2f(x);
#endif
}

__device__ __forceinline__ f32x4 mfma16(bf16x8 a, bf16x8 b, f32x4 c) {
  return __builtin_amdgcn_mfma_f32_16x16x32_bf16(a, b, c, 0, 0, 0);
}

// pack two f32 -> bf16x2 word
__device__ __forceinline__ unsigned pkbf(float a, float b) {
  union { __bf16 h[2]; unsigned u; } t;
  t.h[0] = (__bf16)a; t.h[1] = (__bf16)b;
  return t.u;
}

// v_permlane16_swap_b32: a' = [a(g0), b(g0), a(g2), b(g2)]  (by 16-lane row g)
//                        b' = [a(g1), b(g1), a(g3), b(g3)]
__device__ __forceinline__ void pl16swap(unsigned& a, unsigned& b, int g) {
#if __has_builtin(__builtin_amdgcn_permlane16_swap)
  auto r = __builtin_amdgcn_permlane16_swap(a, b, false, false);
  a = r[0]; b = r[1];
#else
  unsigned as_ = (unsigned)__shfl_xor((int)a, 16, 64);
  unsigned bs_ = (unsigned)__shfl_xor((int)b, 16, 64);
  bool odd = g & 1;
  unsigned an = odd ? bs_ : a;
  unsigned bn = odd ? b : as_;
  a = an; b = bn;
#endif
}

// ---------------------------------------------------------------- fused cvt
// One launch replaces k_cvt_x / k_cvt_wqkv / k_cvt_wo.
//  blocks [0,432):    W_qkv^T via LDS-tiled 64x64 transpose (coalesced reads)
//                     b = t*144 + h*12 + dblk; + bias when dblk==0
//  blocks [432,576):  Wo^T tiles, b-432 = dblk*12 + nblk
//  blocks [576,6720): x fp32 -> bf16 (i = (b-576)*256+tid)
__global__ __launch_bounds__(256) void k_cvt_fused(
    const float* __restrict__ Wq, const float* __restrict__ Wk,
    const float* __restrict__ Wv, const float* __restrict__ bq,
    const float* __restrict__ bk, const float* __restrict__ bv,
    const float* __restrict__ Wo, const float4* __restrict__ x,
    __bf16* __restrict__ Wt, float* __restrict__ bias,
    __bf16* __restrict__ Wot, bf16x4* __restrict__ xb) {
  __shared__ float T[64][68];  // pad 68: 16B-aligned rows, cheap column reads
  const int b = blockIdx.x, tid = threadIdx.x;
  if (b >= 576) {  // ---- x convert (coalesced, proven path)
    int i = (b - 576) * 256 + tid;
    float4 v = x[i];
    bf16x4 o;
    o[0] = (__bf16)v.x; o[1] = (__bf16)v.y; o[2] = (__bf16)v.z; o[3] = (__bf16)v.w;
    xb[i] = o;
    return;
  }
  // ---- 64x64 fp32 tile transpose via LDS
  int r0 = tid >> 4, c4 = (tid & 15) * 4;
  if (b < 432) {
    int t = b / 144, rem = b - t * 144;
    int h = rem / 12, dblk = rem - h * 12;
    const float* W = (t == 0) ? Wq : ((t == 1) ? Wk : Wv);
#pragma unroll
    for (int p = 0; p < 4; ++p) {
      int r = r0 + p * 16;
      float4 v = *(const float4*)&W[(size_t)(h * 768 + dblk * 64 + r) * 64 + c4];
      T[r][c4] = v.x; T[r][c4 + 1] = v.y; T[r][c4 + 2] = v.z; T[r][c4 + 3] = v.w;
    }
    int outn0 = t * 768 + h * 64;
    if (dblk == 0 && tid < 64) {
      const float* bs = (t == 0) ? bq : ((t == 1) ? bk : bv);
      bias[outn0 + tid] = bs[h * 64 + tid];
    }
    __syncthreads();
    int e = tid >> 2, ch = tid & 3;
    union { __bf16 h8[8]; bf16x8 v; } u0, u1;
#pragma unroll
    for (int j = 0; j < 8; ++j) u0.h8[j] = (__bf16)T[ch * 16 + j][e];
#pragma unroll
    for (int j = 0; j < 8; ++j) u1.h8[j] = (__bf16)T[ch * 16 + 8 + j][e];
    __bf16* dst = Wt + (size_t)(outn0 + e) * 768 + dblk * 64 + ch * 16;
    *(bf16x8*)dst = u0.v;
    *(bf16x8*)(dst + 8) = u1.v;
  } else {
    int bb = b - 432;
    int dblk = bb / 12, nblk = bb - dblk * 12;
#pragma unroll
    for (int p = 0; p < 4; ++p) {
      int r = r0 + p * 16;
      float4 v = *(const float4*)&Wo[(size_t)(dblk * 64 + r) * 768 + nblk * 64 + c4];
      T[r][c4] = v.x; T[r][c4 + 1] = v.y; T[r][c4 + 2] = v.z; T[r][c4 + 3] = v.w;
    }
    __syncthreads();
    int e = tid >> 2, ch = tid & 3;
    union { __bf16 h8[8]; bf16x8 v; } u0, u1;
#pragma unroll
    for (int j = 0; j < 8; ++j) u0.h8[j] = (__bf16)T[ch * 16 + j][e];
#pragma unroll
    for (int j = 0; j < 8; ++j) u1.h8[j] = (__bf16)T[ch * 16 + 8 + j][e];
    __bf16* dst = Wot + (size_t)(nblk * 64 + e) * 768 + dblk * 64 + ch * 16;
    *(bf16x8*)dst = u0.v;
    *(bf16x8*)(dst + 8) = u1.v;
  }
}

// ---------------------------------------------------------------- GEMM1
// [R5-proven form, unchanged] C = A[8192][768] * Wqkv^T + bias -> Q/K/V^T
template <int MODE>
__global__ __launch_bounds__(256, 2) void k_gemm(
    const __bf16* __restrict__ A, const __bf16* __restrict__ Bt,
    const float* __restrict__ bias, __bf16* __restrict__ Qd,
    __bf16* __restrict__ Kd, __bf16* __restrict__ VTd,
    float* __restrict__ outF) {
  constexpr int KD = 768;
  __shared__ __bf16 As[2][128 * 64];
  __shared__ __bf16 Bs[2][128 * 64];
  const int tid = threadIdx.x, lane = tid & 63, wid = tid >> 6;
  const int wr = wid >> 1, wc = wid & 1;
  const int bm = blockIdx.x, bn = blockIdx.y;
  const f32x4 z4 = {0.f, 0.f, 0.f, 0.f};
  f32x4 acc[4][4];
#pragma unroll
  for (int a = 0; a < 4; ++a)
#pragma unroll
    for (int b = 0; b < 4; ++b) acc[a][b] = z4;

  const char* Ab = (const char*)A + (size_t)bm * 128 * (KD * 2);
  const char* Bb = (const char*)Bt + (size_t)bn * 128 * (KD * 2);

  auto stage = [&](int kb, int buf) {
#pragma unroll
    for (int i = 0; i < 4; ++i) {
      int o = (wid * 4 + i) * 1024 + lane * 16;
      int row = o >> 7;
      int col = (o & 127) ^ ((row & 7) << 4);  // pre-swizzled source (G21)
      gload16(Ab + (size_t)row * (KD * 2) + kb * 128 + col,
              (char*)As[buf] + (wid * 4 + i) * 1024);
      gload16(Bb + (size_t)row * (KD * 2) + kb * 128 + col,
              (char*)Bs[buf] + (wid * 4 + i) * 1024);
    }
  };

  stage(0, 0);  // prologue

  for (int kb = 0; kb < KD / 64; ++kb) {
    const int cur = kb & 1;
    if (kb < KD / 64 - 1) {
      stage(kb + 1, cur ^ 1);  // next tile in flight during compute
      asm volatile("s_waitcnt vmcnt(8)" ::: "memory");  // this tile's 8 done
    } else {
      asm volatile("s_waitcnt vmcnt(0)" ::: "memory");
    }
    __builtin_amdgcn_s_barrier();
#pragma unroll
    for (int ks = 0; ks < 2; ++ks) {
      bf16x8 af[4], bfr[4];
#pragma unroll
      for (int ar = 0; ar < 4; ++ar) {
        int rl = wr * 64 + ar * 16 + (lane & 15);
        int byt = rl * 128 + ((ks * 64 + (lane >> 4) * 16) ^ ((rl & 7) << 4));
        af[ar] = *(const bf16x8*)((const char*)As[cur] + byt);
      }
#pragma unroll
      for (int bc = 0; bc < 4; ++bc) {
        int rl = wc * 64 + bc * 16 + (lane & 15);
        int byt = rl * 128 + ((ks * 64 + (lane >> 4) * 16) ^ ((rl & 7) << 4));
        bfr[bc] = *(const bf16x8*)((const char*)Bs[cur] + byt);
      }
#pragma unroll
      for (int ar = 0; ar < 4; ++ar)
#pragma unroll
        for (int bc = 0; bc < 4; ++bc)
          acc[ar][bc] = mfma16(af[ar], bfr[bc], acc[ar][bc]);
    }
    __builtin_amdgcn_s_barrier();
  }

#pragma unroll
  for (int ar = 0; ar < 4; ++ar) {
#pragma unroll
    for (int bc = 0; bc < 4; ++bc) {
      int n = bn * 128 + wc * 64 + bc * 16 + (lane & 15);
      float bval = bias[n];
#pragma unroll
      for (int r = 0; r < 4; ++r) {
        int m = bm * 128 + wr * 64 + ar * 16 + (lane >> 4) * 4 + r;
        float val = acc[ar][bc][r] + bval;
        if constexpr (MODE == 0) {
          int t = n / 768;
          int rr = n - t * 768;
          int h = rr >> 6, e = rr & 63;
          int b = m >> 11, s = m & 2047;
          size_t bh = (size_t)(b * 12 + h);
          if (t == 0)
            Qd[(bh * 2048 + s) * 64 + e] = (__bf16)(val * QSCALE);
          else if (t == 1)
            Kd[(bh * 2048 + s) * 64 + e] = (__bf16)val;
          else
            VTd[(bh * 64 + e) * 2048 + s] = (__bf16)val;
        } else {
          outF[(size_t)m * 768 + n] = val;
        }
      }
    }
  }
}

// ---------------------------------------------------------------- GEMM2
// out = attn_out[8192][768] * Wo^T + bo.  64x128 tile -> grid (128,6) = 768
// blocks = exactly 3/CU (fixes 384-block 1.5/CU imbalance of the 128x128
// version). 4 waves 2(M)x2(N), wave 32x64 via 2x4 frags. LDS 48KB dbuf,
// counted vmcnt(6) stage-ahead schedule (R5-proven pattern).
__global__ __launch_bounds__(256, 3) void k_gemm2(
    const __bf16* __restrict__ A, const __bf16* __restrict__ Bt,
    const float* __restrict__ bias, float* __restrict__ outF) {
  constexpr int KD = 768;
  __shared__ __bf16 As[2][64 * 64];
  __shared__ __bf16 Bs[2][128 * 64];
  const int tid = threadIdx.x, lane = tid & 63, wid = tid >> 6;
  const int q = lane & 15, g = lane >> 4;
  const int wr = wid >> 1, wc = wid & 1;
  const int bm = blockIdx.x, bn = blockIdx.y;
  const f32x4 z4 = {0.f, 0.f, 0.f, 0.f};
  f32x4 acc[2][4];
#pragma unroll
  for (int a = 0; a < 2; ++a)
#pragma unroll
    for (int b = 0; b < 4; ++b) acc[a][b] = z4;

  const char* Ab = (const char*)A + (size_t)bm * 64 * (KD * 2);
  const char* Bb = (const char*)Bt + (size_t)bn * 128 * (KD * 2);

  auto stage = [&](int kb, int buf) {
#pragma unroll
    for (int i = 0; i < 2; ++i) {  // A: 8KB = 8 chunks
      int o = (wid * 2 + i) * 1024 + lane * 16;
      int row = o >> 7;
      int col = (o & 127) ^ ((row & 7) << 4);
      gload16(Ab + (size_t)row * (KD * 2) + kb * 128 + col,
              (char*)As[buf] + (wid * 2 + i) * 1024);
    }
#pragma unroll
    for (int i = 0; i < 4; ++i) {  // B: 16KB = 16 chunks
      int o = (wid * 4 + i) * 1024 + lane * 16;
      int row = o >> 7;
      int col = (o & 127) ^ ((row & 7) << 4);
      gload16(Bb + (size_t)row * (KD * 2) + kb * 128 + col,
              (char*)Bs[buf] + (wid * 4 + i) * 1024);
    }
  };

  stage(0, 0);

  for (int kb = 0; kb < KD / 64; ++kb) {
    const int cur = kb & 1;
    if (kb < KD / 64 - 1) {
      stage(kb + 1, cur ^ 1);
      asm volatile("s_waitcnt vmcnt(6)" ::: "memory");  // this tile's 6 done
    } else {
      asm volatile("s_waitcnt vmcnt(0)" ::: "memory");
    }
    __builtin_amdgcn_s_barrier();
#pragma unroll
    for (int ks = 0; ks < 2; ++ks) {
      bf16x8 af[2], bfr[4];
#pragma unroll
      for (int ar = 0; ar < 2; ++ar) {
        int rl = wr * 32 + ar * 16 + q;
        int byt = rl * 128 + ((ks * 64 + g * 16) ^ ((rl & 7) << 4));
        af[ar] = *(const bf16x8*)((const char*)As[cur] + byt);
      }
#pragma unroll
      for (int bc = 0; bc < 4; ++bc) {
        int rl = wc * 64 + bc * 16 + q;
        int byt = rl * 128 + ((ks * 64 + g * 16) ^ ((rl & 7) << 4));
        bfr[bc] = *(const bf16x8*)((const char*)Bs[cur] + byt);
      }
#pragma unroll
      for (int ar = 0; ar < 2; ++ar)
#pragma unroll
        for (int bc = 0; bc < 4; ++bc)
          acc[ar][bc] = mfma16(af[ar], bfr[bc], acc[ar][bc]);
    }
    __builtin_amdgcn_s_barrier();
  }

#pragma unroll
  for (int ar = 0; ar < 2; ++ar) {
#pragma unroll
    for (int bc = 0; bc < 4; ++bc) {
      int n = bn * 128 + wc * 64 + bc * 16 + q;
      float bval = bias[n];
#pragma unroll
      for (int r = 0; r < 4; ++r) {
        int m = bm * 64 + wr * 32 + ar * 16 + g * 4 + r;
        outF[(size_t)m * 768 + n] = acc[ar][bc][r] + bval;
      }
    }
  }
}

// ---------------------------------------------------------------- flash attn
// EXACT R8 kernel (proven best: 73.3us). Swapped-operand, P in registers,
// NO-MAX softmax, QBLK=128 4 waves x 32 q-rows, XCD swizzle, triple-buffered
// K/V with counted vmcnt(4), depth-2 pipeline {V,SM | barrier | QK(t+1) | PV}.
__global__ __launch_bounds__(256, 3) void k_attn(const __bf16* __restrict__ Qg,
                                                 const __bf16* __restrict__ Kg,
                                                 const __bf16* __restrict__ Vg,
                                                 __bf16* __restrict__ AO) {
  constexpr int S = 2048;
  constexpr int NT = S / 64;  // 32 kv tiles
  __shared__ __bf16 Ks[3][64 * 64];
  __shared__ __bf16 Vs[3][64 * 64];
  const int tid = threadIdx.x, lane = tid & 63, wid = tid >> 6;
  const int q = lane & 15, g = lane >> 4;
  const int q7s = (q & 7) << 4;
  const int vg = ((g & 1) << 5) | ((g >> 1) << 4);  // permuted V col base (bytes)
  const int lin = blockIdx.x + blockIdx.y * 16;  // 0..767
  const int xcd = lin & 7, pos = lin >> 3;       // pos 0..95
  const int bh = xcd * 6 + (pos >> 4);
  const int qt = pos & 15;
  const int bb = bh / 12, hh = bh - bb * 12;
  const size_t hoff = (size_t)bh * S * 64;
  const int q0 = qt * 128 + wid * 32;

  bf16x8 qb[2][2];
#pragma unroll
  for (int rt = 0; rt < 2; ++rt)
#pragma unroll
    for (int ks = 0; ks < 2; ++ks)
      qb[rt][ks] = *(const bf16x8*)(Qg + hoff + (size_t)(q0 + rt * 16 + q) * 64 +
                                    ks * 32 + g * 8);

  const f32x4 z4 = {0.f, 0.f, 0.f, 0.f};
  f32x4 acc[2][4];
#pragma unroll
  for (int a = 0; a < 2; ++a)
#pragma unroll
    for (int b = 0; b < 4; ++b) acc[a][b] = z4;
  float l_p[2] = {0.f, 0.f};

  const char* Kb = (const char*)(Kg + hoff);
  const char* Vb = (const char*)(Vg + (size_t)bh * 64 * S);

  auto stage = [&](int kv, int buf) {
#pragma unroll
    for (int i = 0; i < 2; ++i) {
      int o = (wid * 2 + i) * 1024 + lane * 16;
      int row = o >> 7;
      int col = (o & 127) ^ ((row & 7) << 4);
      gload16(Kb + (size_t)(kv * 64 + row) * 128 + col,
              (char*)Ks[buf] + (wid * 2 + i) * 1024);
      gload16(Vb + (size_t)row * (S * 2) + (size_t)kv * 128 + col,
              (char*)Vs[buf] + (wid * 2 + i) * 1024);
    }
  };

  auto qk = [&](const char* Kc, f32x4 (&sa)[4][2]) {
#pragma unroll
    for (int ct = 0; ct < 4; ++ct) {
      sa[ct][0] = z4;
      sa[ct][1] = z4;
    }
    __builtin_amdgcn_s_setprio(1);
#pragma unroll
    for (int ks = 0; ks < 2; ++ks)
#pragma unroll
      for (int ct = 0; ct < 4; ++ct) {
        int rl = ct * 16 + q;
        bf16x8 ka = *(const bf16x8*)(Kc + rl * 128 + ((ks * 64 + g * 16) ^ q7s));
        sa[ct][0] = mfma16(ka, qb[0][ks], sa[ct][0]);
        sa[ct][1] = mfma16(ka, qb[1][ks], sa[ct][1]);
      }
    __builtin_amdgcn_s_setprio(0);
  };

  stage(0, 0);
  stage(1, 1);
  asm volatile("s_waitcnt vmcnt(4)" ::: "memory");
  __builtin_amdgcn_s_barrier();

  f32x4 sa[4][2];
  qk((const char*)Ks[0], sa);  // QK(0)

  for (int kv = 0; kv < NT; ++kv) {
    if (kv < NT - 2) stage(kv + 2, (kv + 2) % 3);
    const char* Vc = (const char*)Vs[kv % 3];

    bf16x8 vf[2][4];
#pragma unroll
    for (int ks = 0; ks < 2; ++ks)
#pragma unroll
      for (int et = 0; et < 4; ++et) {
        int rl = et * 16 + q;
        vf[ks][et] = *(const bf16x8*)(Vc + rl * 128 + ((ks * 64 + vg) ^ q7s));
      }

    bf16x8 pb[2][2];
#pragma unroll
    for (int rt = 0; rt < 2; ++rt) {
      float sum = 0.f;
      unsigned w[4][2];
#pragma unroll
      for (int ct = 0; ct < 4; ++ct) {
        float p0 = fexp2(sa[ct][rt][0]);
        float p1 = fexp2(sa[ct][rt][1]);
        float p2 = fexp2(sa[ct][rt][2]);
        float p3 = fexp2(sa[ct][rt][3]);
        sum += (p0 + p1) + (p2 + p3);
        w[ct][0] = pkbf(p0, p1);
        w[ct][1] = pkbf(p2, p3);
      }
      l_p[rt] += sum;
      pl16swap(w[0][0], w[1][0], g);
      pl16swap(w[0][1], w[1][1], g);
      pl16swap(w[2][0], w[3][0], g);
      pl16swap(w[2][1], w[3][1], g);
      union { unsigned u[4]; bf16x8 v; } f0, f1;
      f0.u[0] = w[0][0]; f0.u[1] = w[0][1]; f0.u[2] = w[1][0]; f0.u[3] = w[1][1];
      f1.u[0] = w[2][0]; f1.u[1] = w[2][1]; f1.u[2] = w[3][0]; f1.u[3] = w[3][1];
      pb[rt][0] = f0.v;
      pb[rt][1] = f1.v;
    }

    if (kv < NT - 1) {
      if (kv < NT - 2) {
        asm volatile("s_waitcnt vmcnt(4)" ::: "memory");
      } else {
        asm volatile("s_waitcnt vmcnt(0)" ::: "memory");
      }
      __builtin_amdgcn_s_barrier();
      qk((const char*)Ks[(kv + 1) % 3], sa);
    }

    __builtin_amdgcn_s_setprio(1);
#pragma unroll
    for (int ks = 0; ks < 2; ++ks)
#pragma unroll
      for (int et = 0; et < 4; ++et) {
        acc[0][et] = mfma16(vf[ks][et], pb[0][ks], acc[0][et]);
        acc[1][et] = mfma16(vf[ks][et], pb[1][ks], acc[1][et]);
      }
    __builtin_amdgcn_s_setprio(0);
  }

#pragma unroll
  for (int rt = 0; rt < 2; ++rt) {
    float l = l_p[rt];
    l += __shfl_xor(l, 16, 64);
    l += __shfl_xor(l, 32, 64);
    float inv = 1.0f / l;
    int srow = q0 + rt * 16 + q;
#pragma unroll
    for (int et = 0; et < 4; ++et) {
      bf16x4 ov;
#pragma unroll
      for (int r = 0; r < 4; ++r) ov[r] = (__bf16)(acc[rt][et][r] * inv);
      *(bf16x4*)(AO + ((size_t)bb * S + srow) * 768 + hh * 64 + et * 16 + g * 4) =
          ov;
    }
  }
}

// ---------------------------------------------------------------- launch
extern "C" void kernel_launch(void* const* d_in, const int* in_sizes, int n_in,
                              void* d_out, int out_size, void* d_ws,
                              size_t ws_size, hipStream_t stream) {
  const float* x = (const float*)d_in[0];
  const float* Wq = (const float*)d_in[1];
  const float* bq = (const float*)d_in[2];
  const float* Wk = (const float*)d_in[3];
  const float* bk = (const float*)d_in[4];
  const float* Wv = (const float*)d_in[5];
  const float* bv = (const float*)d_in[6];
  const float* Wo = (const float*)d_in[7];
  const float* bo = (const float*)d_in[8];
  float* out = (float*)d_out;
  char* ws = (char*)d_ws;

  // workspace layout (55.06 MB total)
  __bf16* xb = (__bf16*)(ws + 0);            // 12,582,912  (also attn_out later)
  __bf16* wqkv = (__bf16*)(ws + 12582912);   //  3,538,944
  __bf16* wot = (__bf16*)(ws + 16121856);    //  1,179,648
  float* biasq = (float*)(ws + 17301504);    //      9,216
  __bf16* Qb = (__bf16*)(ws + 17310720);     // 12,582,912
  __bf16* Kb = (__bf16*)(ws + 29893632);     // 12,582,912
  __bf16* VT = (__bf16*)(ws + 42476544);     // 12,582,912 -> end 55,059,456

  k_cvt_fused<<<6720, 256, 0, stream>>>(Wq, Wk, Wv, bq, bk, bv, Wo,
                                        (const float4*)x, wqkv, biasq, wot,
                                        (bf16x4*)xb);
  k_gemm<0><<<dim3(64, 18), 256, 0, stream>>>(xb, wqkv, biasq, Qb, Kb, VT,
                                              nullptr);
  k_attn<<<dim3(16, 48), 256, 0, stream>>>(Qb, Kb, VT, xb /*attn_out*/);
  k_gemm2<<<dim3(128, 6), 256, 0, stream>>>(xb, wot, bo, out);
}

// Round 11
// 141.605 us; speedup vs baseline: 1.2371x; 1.0464x over previous
//
#include <hip/hip_runtime.h>

typedef __bf16 bf16x8 __attribute__((ext_vector_type(8)));
typedef __bf16 bf16x4 __attribute__((ext_vector_type(4)));
typedef float f32x4 __attribute__((ext_vector_type(4)));

#define QSCALE 0.18033688011112042f /* 0.125 * log2(e) */

__device__ __forceinline__ void gload16(const void* g, void* l) {
  __builtin_amdgcn_global_load_lds((const __attribute__((address_space(1))) void*)g,
                                   (__attribute__((address_space(3))) void*)l, 16, 0, 0);
}

__device__ __forceinline__ float fexp2(float x) {
#if __has_builtin(__builtin_amdgcn_exp2f)
  return __builtin_amdgcn_exp2f(x);
#else
  return exp2f(x);
#endif
}

__device__ __forceinline__ f32x4 mfma16(bf16x8 a, bf16x8 b, f32x4 c) {
  return __builtin_amdgcn_mfma_f32_16x16x32_bf16(a, b, c, 0, 0, 0);
}

// pack two f32 -> bf16x2 word
__device__ __forceinline__ unsigned pkbf(float a, float b) {
  union { __bf16 h[2]; unsigned u; } t;
  t.h[0] = (__bf16)a; t.h[1] = (__bf16)b;
  return t.u;
}

// v_permlane16_swap_b32: a' = [a(g0), b(g0), a(g2), b(g2)]  (by 16-lane row g)
//                        b' = [a(g1), b(g1), a(g3), b(g3)]
__device__ __forceinline__ void pl16swap(unsigned& a, unsigned& b, int g) {
#if __has_builtin(__builtin_amdgcn_permlane16_swap)
  auto r = __builtin_amdgcn_permlane16_swap(a, b, false, false);
  a = r[0]; b = r[1];
#else
  unsigned as_ = (unsigned)__shfl_xor((int)a, 16, 64);
  unsigned bs_ = (unsigned)__shfl_xor((int)b, 16, 64);
  bool odd = g & 1;
  unsigned an = odd ? bs_ : a;
  unsigned bn = odd ? b : as_;
  a = an; b = bn;
#endif
}

// ---------------------------------------------------------------- fused cvt
// [R10-proven form, unchanged]
//  blocks [0,432):    W_qkv^T via LDS-tiled 64x64 transpose + bias
//  blocks [432,576):  Wo^T tiles
//  blocks [576,6720): x fp32 -> bf16
__global__ __launch_bounds__(256) void k_cvt_fused(
    const float* __restrict__ Wq, const float* __restrict__ Wk,
    const float* __restrict__ Wv, const float* __restrict__ bq,
    const float* __restrict__ bk, const float* __restrict__ bv,
    const float* __restrict__ Wo, const float4* __restrict__ x,
    __bf16* __restrict__ Wt, float* __restrict__ bias,
    __bf16* __restrict__ Wot, bf16x4* __restrict__ xb) {
  __shared__ float T[64][68];
  const int b = blockIdx.x, tid = threadIdx.x;
  if (b >= 576) {
    int i = (b - 576) * 256 + tid;
    float4 v = x[i];
    bf16x4 o;
    o[0] = (__bf16)v.x; o[1] = (__bf16)v.y; o[2] = (__bf16)v.z; o[3] = (__bf16)v.w;
    xb[i] = o;
    return;
  }
  int r0 = tid >> 4, c4 = (tid & 15) * 4;
  if (b < 432) {
    int t = b / 144, rem = b - t * 144;
    int h = rem / 12, dblk = rem - h * 12;
    const float* W = (t == 0) ? Wq : ((t == 1) ? Wk : Wv);
#pragma unroll
    for (int p = 0; p < 4; ++p) {
      int r = r0 + p * 16;
      float4 v = *(const float4*)&W[(size_t)(h * 768 + dblk * 64 + r) * 64 + c4];
      T[r][c4] = v.x; T[r][c4 + 1] = v.y; T[r][c4 + 2] = v.z; T[r][c4 + 3] = v.w;
    }
    int outn0 = t * 768 + h * 64;
    if (dblk == 0 && tid < 64) {
      const float* bs = (t == 0) ? bq : ((t == 1) ? bk : bv);
      bias[outn0 + tid] = bs[h * 64 + tid];
    }
    __syncthreads();
    int e = tid >> 2, ch = tid & 3;
    union { __bf16 h8[8]; bf16x8 v; } u0, u1;
#pragma unroll
    for (int j = 0; j < 8; ++j) u0.h8[j] = (__bf16)T[ch * 16 + j][e];
#pragma unroll
    for (int j = 0; j < 8; ++j) u1.h8[j] = (__bf16)T[ch * 16 + 8 + j][e];
    __bf16* dst = Wt + (size_t)(outn0 + e) * 768 + dblk * 64 + ch * 16;
    *(bf16x8*)dst = u0.v;
    *(bf16x8*)(dst + 8) = u1.v;
  } else {
    int bb = b - 432;
    int dblk = bb / 12, nblk = bb - dblk * 12;
#pragma unroll
    for (int p = 0; p < 4; ++p) {
      int r = r0 + p * 16;
      float4 v = *(const float4*)&Wo[(size_t)(dblk * 64 + r) * 768 + nblk * 64 + c4];
      T[r][c4] = v.x; T[r][c4 + 1] = v.y; T[r][c4 + 2] = v.z; T[r][c4 + 3] = v.w;
    }
    __syncthreads();
    int e = tid >> 2, ch = tid & 3;
    union { __bf16 h8[8]; bf16x8 v; } u0, u1;
#pragma unroll
    for (int j = 0; j < 8; ++j) u0.h8[j] = (__bf16)T[ch * 16 + j][e];
#pragma unroll
    for (int j = 0; j < 8; ++j) u1.h8[j] = (__bf16)T[ch * 16 + 8 + j][e];
    __bf16* dst = Wot + (size_t)(nblk * 64 + e) * 768 + dblk * 64 + ch * 16;
    *(bf16x8*)dst = u0.v;
    *(bf16x8*)(dst + 8) = u1.v;
  }
}

// ---------------------------------------------------------------- GEMM
// Unified 64(M)x128(N) tile, BK=64, 4 waves 2(M)x2(N), wave 32x64 via 2x4
// frags. LDS 48KB dbuf -> 3 blocks/CU. Counted vmcnt(6) stage-ahead schedule
// (R10-proven on gemm2; now also gemm1 -> grid (128,18) = 2304 = exactly 3
// full rounds of 768 concurrent blocks, fixing the 2.25-round tail of the
// old 128x128 version). A-tile 18x re-reads hit one XCD (XCD=bm%8, 128%8=0).
// MODE 0: scatter to Q/K/V^T bf16 (Q scaled by QSCALE). MODE 1: fp32 out.
template <int MODE>
__global__ __launch_bounds__(256, 3) void k_gemmB(
    const __bf16* __restrict__ A, const __bf16* __restrict__ Bt,
    const float* __restrict__ bias, __bf16* __restrict__ Qd,
    __bf16* __restrict__ Kd, __bf16* __restrict__ VTd,
    float* __restrict__ outF) {
  constexpr int KD = 768;
  __shared__ __bf16 As[2][64 * 64];
  __shared__ __bf16 Bs[2][128 * 64];
  const int tid = threadIdx.x, lane = tid & 63, wid = tid >> 6;
  const int q = lane & 15, g = lane >> 4;
  const int wr = wid >> 1, wc = wid & 1;
  const int bm = blockIdx.x, bn = blockIdx.y;
  const f32x4 z4 = {0.f, 0.f, 0.f, 0.f};
  f32x4 acc[2][4];
#pragma unroll
  for (int a = 0; a < 2; ++a)
#pragma unroll
    for (int b = 0; b < 4; ++b) acc[a][b] = z4;

  const char* Ab = (const char*)A + (size_t)bm * 64 * (KD * 2);
  const char* Bb = (const char*)Bt + (size_t)bn * 128 * (KD * 2);

  auto stage = [&](int kb, int buf) {
#pragma unroll
    for (int i = 0; i < 2; ++i) {  // A: 8KB = 8 chunks
      int o = (wid * 2 + i) * 1024 + lane * 16;
      int row = o >> 7;
      int col = (o & 127) ^ ((row & 7) << 4);
      gload16(Ab + (size_t)row * (KD * 2) + kb * 128 + col,
              (char*)As[buf] + (wid * 2 + i) * 1024);
    }
#pragma unroll
    for (int i = 0; i < 4; ++i) {  // B: 16KB = 16 chunks
      int o = (wid * 4 + i) * 1024 + lane * 16;
      int row = o >> 7;
      int col = (o & 127) ^ ((row & 7) << 4);
      gload16(Bb + (size_t)row * (KD * 2) + kb * 128 + col,
              (char*)Bs[buf] + (wid * 4 + i) * 1024);
    }
  };

  stage(0, 0);

  for (int kb = 0; kb < KD / 64; ++kb) {
    const int cur = kb & 1;
    if (kb < KD / 64 - 1) {
      stage(kb + 1, cur ^ 1);
      asm volatile("s_waitcnt vmcnt(6)" ::: "memory");  // this tile's 6 done
    } else {
      asm volatile("s_waitcnt vmcnt(0)" ::: "memory");
    }
    __builtin_amdgcn_s_barrier();
#pragma unroll
    for (int ks = 0; ks < 2; ++ks) {
      bf16x8 af[2], bfr[4];
#pragma unroll
      for (int ar = 0; ar < 2; ++ar) {
        int rl = wr * 32 + ar * 16 + q;
        int byt = rl * 128 + ((ks * 64 + g * 16) ^ ((rl & 7) << 4));
        af[ar] = *(const bf16x8*)((const char*)As[cur] + byt);
      }
#pragma unroll
      for (int bc = 0; bc < 4; ++bc) {
        int rl = wc * 64 + bc * 16 + q;
        int byt = rl * 128 + ((ks * 64 + g * 16) ^ ((rl & 7) << 4));
        bfr[bc] = *(const bf16x8*)((const char*)Bs[cur] + byt);
      }
#pragma unroll
      for (int ar = 0; ar < 2; ++ar)
#pragma unroll
        for (int bc = 0; bc < 4; ++bc)
          acc[ar][bc] = mfma16(af[ar], bfr[bc], acc[ar][bc]);
    }
    __builtin_amdgcn_s_barrier();
  }

#pragma unroll
  for (int ar = 0; ar < 2; ++ar) {
#pragma unroll
    for (int bc = 0; bc < 4; ++bc) {
      int n = bn * 128 + wc * 64 + bc * 16 + q;
      float bval = bias[n];
#pragma unroll
      for (int r = 0; r < 4; ++r) {
        int m = bm * 64 + wr * 32 + ar * 16 + g * 4 + r;
        float val = acc[ar][bc][r] + bval;
        if constexpr (MODE == 0) {
          int t = n / 768;
          int rr = n - t * 768;
          int h = rr >> 6, e = rr & 63;
          int b = m >> 11, s = m & 2047;
          size_t bh = (size_t)(b * 12 + h);
          if (t == 0)
            Qd[(bh * 2048 + s) * 64 + e] = (__bf16)(val * QSCALE);
          else if (t == 1)
            Kd[(bh * 2048 + s) * 64 + e] = (__bf16)val;
          else
            VTd[(bh * 64 + e) * 2048 + s] = (__bf16)val;
        } else {
          outF[(size_t)m * 768 + n] = val;
        }
      }
    }
  }
}

// ---------------------------------------------------------------- flash attn
// EXACT R8 kernel (proven best: 73.3us). Swapped-operand, P in registers,
// NO-MAX softmax, QBLK=128 4 waves x 32 q-rows, XCD swizzle, triple-buffered
// K/V with counted vmcnt(4), depth-2 pipeline {V,SM | barrier | QK(t+1) | PV}.
__global__ __launch_bounds__(256, 3) void k_attn(const __bf16* __restrict__ Qg,
                                                 const __bf16* __restrict__ Kg,
                                                 const __bf16* __restrict__ Vg,
                                                 __bf16* __restrict__ AO) {
  constexpr int S = 2048;
  constexpr int NT = S / 64;  // 32 kv tiles
  __shared__ __bf16 Ks[3][64 * 64];
  __shared__ __bf16 Vs[3][64 * 64];
  const int tid = threadIdx.x, lane = tid & 63, wid = tid >> 6;
  const int q = lane & 15, g = lane >> 4;
  const int q7s = (q & 7) << 4;
  const int vg = ((g & 1) << 5) | ((g >> 1) << 4);  // permuted V col base (bytes)
  const int lin = blockIdx.x + blockIdx.y * 16;  // 0..767
  const int xcd = lin & 7, pos = lin >> 3;       // pos 0..95
  const int bh = xcd * 6 + (pos >> 4);
  const int qt = pos & 15;
  const int bb = bh / 12, hh = bh - bb * 12;
  const size_t hoff = (size_t)bh * S * 64;
  const int q0 = qt * 128 + wid * 32;

  bf16x8 qb[2][2];
#pragma unroll
  for (int rt = 0; rt < 2; ++rt)
#pragma unroll
    for (int ks = 0; ks < 2; ++ks)
      qb[rt][ks] = *(const bf16x8*)(Qg + hoff + (size_t)(q0 + rt * 16 + q) * 64 +
                                    ks * 32 + g * 8);

  const f32x4 z4 = {0.f, 0.f, 0.f, 0.f};
  f32x4 acc[2][4];
#pragma unroll
  for (int a = 0; a < 2; ++a)
#pragma unroll
    for (int b = 0; b < 4; ++b) acc[a][b] = z4;
  float l_p[2] = {0.f, 0.f};

  const char* Kb = (const char*)(Kg + hoff);
  const char* Vb = (const char*)(Vg + (size_t)bh * 64 * S);

  auto stage = [&](int kv, int buf) {
#pragma unroll
    for (int i = 0; i < 2; ++i) {
      int o = (wid * 2 + i) * 1024 + lane * 16;
      int row = o >> 7;
      int col = (o & 127) ^ ((row & 7) << 4);
      gload16(Kb + (size_t)(kv * 64 + row) * 128 + col,
              (char*)Ks[buf] + (wid * 2 + i) * 1024);
      gload16(Vb + (size_t)row * (S * 2) + (size_t)kv * 128 + col,
              (char*)Vs[buf] + (wid * 2 + i) * 1024);
    }
  };

  auto qk = [&](const char* Kc, f32x4 (&sa)[4][2]) {
#pragma unroll
    for (int ct = 0; ct < 4; ++ct) {
      sa[ct][0] = z4;
      sa[ct][1] = z4;
    }
    __builtin_amdgcn_s_setprio(1);
#pragma unroll
    for (int ks = 0; ks < 2; ++ks)
#pragma unroll
      for (int ct = 0; ct < 4; ++ct) {
        int rl = ct * 16 + q;
        bf16x8 ka = *(const bf16x8*)(Kc + rl * 128 + ((ks * 64 + g * 16) ^ q7s));
        sa[ct][0] = mfma16(ka, qb[0][ks], sa[ct][0]);
        sa[ct][1] = mfma16(ka, qb[1][ks], sa[ct][1]);
      }
    __builtin_amdgcn_s_setprio(0);
  };

  stage(0, 0);
  stage(1, 1);
  asm volatile("s_waitcnt vmcnt(4)" ::: "memory");
  __builtin_amdgcn_s_barrier();

  f32x4 sa[4][2];
  qk((const char*)Ks[0], sa);  // QK(0)

  for (int kv = 0; kv < NT; ++kv) {
    if (kv < NT - 2) stage(kv + 2, (kv + 2) % 3);
    const char* Vc = (const char*)Vs[kv % 3];

    bf16x8 vf[2][4];
#pragma unroll
    for (int ks = 0; ks < 2; ++ks)
#pragma unroll
      for (int et = 0; et < 4; ++et) {
        int rl = et * 16 + q;
        vf[ks][et] = *(const bf16x8*)(Vc + rl * 128 + ((ks * 64 + vg) ^ q7s));
      }

    bf16x8 pb[2][2];
#pragma unroll
    for (int rt = 0; rt < 2; ++rt) {
      float sum = 0.f;
      unsigned w[4][2];
#pragma unroll
      for (int ct = 0; ct < 4; ++ct) {
        float p0 = fexp2(sa[ct][rt][0]);
        float p1 = fexp2(sa[ct][rt][1]);
        float p2 = fexp2(sa[ct][rt][2]);
        float p3 = fexp2(sa[ct][rt][3]);
        sum += (p0 + p1) + (p2 + p3);
        w[ct][0] = pkbf(p0, p1);
        w[ct][1] = pkbf(p2, p3);
      }
      l_p[rt] += sum;
      pl16swap(w[0][0], w[1][0], g);
      pl16swap(w[0][1], w[1][1], g);
      pl16swap(w[2][0], w[3][0], g);
      pl16swap(w[2][1], w[3][1], g);
      union { unsigned u[4]; bf16x8 v; } f0, f1;
      f0.u[0] = w[0][0]; f0.u[1] = w[0][1]; f0.u[2] = w[1][0]; f0.u[3] = w[1][1];
      f1.u[0] = w[2][0]; f1.u[1] = w[2][1]; f1.u[2] = w[3][0]; f1.u[3] = w[3][1];
      pb[rt][0] = f0.v;
      pb[rt][1] = f1.v;
    }

    if (kv < NT - 1) {
      if (kv < NT - 2) {
        asm volatile("s_waitcnt vmcnt(4)" ::: "memory");
      } else {
        asm volatile("s_waitcnt vmcnt(0)" ::: "memory");
      }
      __builtin_amdgcn_s_barrier();
      qk((const char*)Ks[(kv + 1) % 3], sa);
    }

    __builtin_amdgcn_s_setprio(1);
#pragma unroll
    for (int ks = 0; ks < 2; ++ks)
#pragma unroll
      for (int et = 0; et < 4; ++et) {
        acc[0][et] = mfma16(vf[ks][et], pb[0][ks], acc[0][et]);
        acc[1][et] = mfma16(vf[ks][et], pb[1][ks], acc[1][et]);
      }
    __builtin_amdgcn_s_setprio(0);
  }

#pragma unroll
  for (int rt = 0; rt < 2; ++rt) {
    float l = l_p[rt];
    l += __shfl_xor(l, 16, 64);
    l += __shfl_xor(l, 32, 64);
    float inv = 1.0f / l;
    int srow = q0 + rt * 16 + q;
#pragma unroll
    for (int et = 0; et < 4; ++et) {
      bf16x4 ov;
#pragma unroll
      for (int r = 0; r < 4; ++r) ov[r] = (__bf16)(acc[rt][et][r] * inv);
      *(bf16x4*)(AO + ((size_t)bb * S + srow) * 768 + hh * 64 + et * 16 + g * 4) =
          ov;
    }
  }
}

// ---------------------------------------------------------------- launch
extern "C" void kernel_launch(void* const* d_in, const int* in_sizes, int n_in,
                              void* d_out, int out_size, void* d_ws,
                              size_t ws_size, hipStream_t stream) {
  const float* x = (const float*)d_in[0];
  const float* Wq = (const float*)d_in[1];
  const float* bq = (const float*)d_in[2];
  const float* Wk = (const float*)d_in[3];
  const float* bk = (const float*)d_in[4];
  const float* Wv = (const float*)d_in[5];
  const float* bv = (const float*)d_in[6];
  const float* Wo = (const float*)d_in[7];
  const float* bo = (const float*)d_in[8];
  float* out = (float*)d_out;
  char* ws = (char*)d_ws;

  // workspace layout (55.06 MB total)
  __bf16* xb = (__bf16*)(ws + 0);            // 12,582,912  (also attn_out later)
  __bf16* wqkv = (__bf16*)(ws + 12582912);   //  3,538,944
  __bf16* wot = (__bf16*)(ws + 16121856);    //  1,179,648
  float* biasq = (float*)(ws + 17301504);    //      9,216
  __bf16* Qb = (__bf16*)(ws + 17310720);     // 12,582,912
  __bf16* Kb = (__bf16*)(ws + 29893632);     // 12,582,912
  __bf16* VT = (__bf16*)(ws + 42476544);     // 12,582,912 -> end 55,059,456

  k_cvt_fused<<<6720, 256, 0, stream>>>(Wq, Wk, Wv, bq, bk, bv, Wo,
                                        (const float4*)x, wqkv, biasq, wot,
                                        (bf16x4*)xb);
  k_gemmB<0><<<dim3(128, 18), 256, 0, stream>>>(xb, wqkv, biasq, Qb, Kb, VT,
                                                nullptr);
  k_attn<<<dim3(16, 48), 256, 0, stream>>>(Qb, Kb, VT, xb /*attn_out*/);
  k_gemmB<1><<<dim3(128, 6), 256, 0, stream>>>(xb, wot, bo, nullptr, nullptr,
                                               nullptr, out);
}